// Round 3
// baseline (345.545 us; speedup 1.0000x reference)
//
#include <hip/hip_runtime.h>
#include <hip/hip_bf16.h>

// Swin block, B=32 H=W=56 C=128, ws=7 (N=49), nh=4 (hd=32), shift=3, hid=512.
// fp32 in/out. All GEMMs AND attention (QK^T, AV) via mfma_f32_16x16x32_bf16.
// roll(-3) gather == roll(+3) scatter target -> fully fused windows.
// R8: 1024 threads/block (16 waves). Same 76800 B LDS -> still 2 blocks/CU but
//     32 waves/CU (8/SIMD, the HW cap) vs 16: kernel remains latency-bound
//     (MfmaUtil 13%, VALU 37%, HBM 7%). Per-wave work halves again:
//     QKV = 3 tiles x m-half (24 MFMA), attn = (head, query-16-tile)/wave,
//     proj/GEMM2 = (col-tile, m-half)/wave, GEMM1 = one j-16-tile/wave.
//     __launch_bounds__(1024,8) -> 64 VGPR budget (R7 fit 64 w/ bigger tiles).

#define NWIN 2048

typedef short short8  __attribute__((ext_vector_type(8)));
typedef short short4v __attribute__((ext_vector_type(4)));
typedef float f32x4   __attribute__((ext_vector_type(4)));

#define QKVW_OFF  0        // 384*128 bf16
#define PROJW_OFF 49152    // 128*128
#define W1_OFF    65536    // 512*128
#define W2_OFF    131072   // 128*512
#define BIAS_BYTE_OFF 393216  // biasT[4][64][64] fp32 (padded, 0 outside 49x49)

__device__ __forceinline__ short f2bs(float v) {
  __hip_bfloat16 h = __float2bfloat16(v);
  union { __hip_bfloat16 h; short s; } u; u.h = h; return u.s;
}
__device__ __forceinline__ float gelu_f(float v) {
  float u = v * (0.7978845608028654f + 0.03567740814f * v * v);
  return v * __builtin_amdgcn_rcpf(1.f + __expf(-2.f * u));
}

// ---------------- pre-pass: weights -> bf16, padded bias^T gather ----------------
__global__ __launch_bounds__(256) void conv_kernel(
    const float* __restrict__ qkvw, const float* __restrict__ projw,
    const float* __restrict__ w1,   const float* __restrict__ w2,
    const float* __restrict__ tab,  const int* __restrict__ ridx,
    __hip_bfloat16* __restrict__ wsb, float* __restrict__ biasT)
{
  int idx = blockIdx.x * 256 + threadIdx.x;
  if (idx < 49152)       wsb[QKVW_OFF + idx]          = __float2bfloat16(qkvw[idx]);
  else if (idx < 65536)  wsb[PROJW_OFF + idx - 49152] = __float2bfloat16(projw[idx - 49152]);
  else if (idx < 131072) wsb[W1_OFF + idx - 65536]    = __float2bfloat16(w1[idx - 65536]);
  else if (idx < 196608) wsb[W2_OFF + idx - 131072]   = __float2bfloat16(w2[idx - 131072]);
  else if (idx < 212992) {
    int i = idx - 196608;
    int h = i >> 12, m = (i >> 6) & 63, n = i & 63;   // biasT[h][m=key][n=query]
    biasT[i] = (m < 49 && n < 49) ? tab[ridx[n*49 + m]*4 + h] : 0.f;
  }
}

// ------- fused: LN1 + window attn + proj + shortcut + LN2 + MLP + residual -------
__global__ __launch_bounds__(1024, 8) void fused_kernel(
    const float* __restrict__ x,
    const float* __restrict__ n1g, const float* __restrict__ n1b,
    const __hip_bfloat16* __restrict__ qkvwb, const float* __restrict__ qkvb,
    const float* __restrict__ biasT,
    const __hip_bfloat16* __restrict__ projwb, const float* __restrict__ projb,
    const float* __restrict__ n2g, const float* __restrict__ n2b,
    const __hip_bfloat16* __restrict__ w1b, const float* __restrict__ b1,
    const __hip_bfloat16* __restrict__ w2b, const float* __restrict__ b2,
    float* __restrict__ out)
{
  __shared__ alignas(16) __hip_bfloat16 hbuf[64][136];   // 17408 B: h / o / ln2
  __shared__ alignas(16) char regA[40960];               // qk | x2s fp32 | hidden
  __shared__ alignas(16) __hip_bfloat16 vT[4][32][72];   // 18432 B
  __hip_bfloat16* const qkb = (__hip_bfloat16*)regA;     // qk[4][2][64][40]
  float*          const x2s = (float*)regA;              // [64][132] fp32 (33792 B)
  __hip_bfloat16* const hb  = (__hip_bfloat16*)regA;     // [64][264] (33792 B)

  const int tid = threadIdx.x, wave = tid >> 6, lane = tid & 63;
  const int l15 = lane & 15, quad = lane >> 4;
  const int wlo = wave & 7, mh = wave >> 3;              // col-tile, m-half
  const int b = blockIdx.x >> 6, wi = (blockIdx.x >> 3) & 7, wj = blockIdx.x & 7;

  // ---- phase 1: LN1 over source rows (roll -3) -> hbuf bf16 ----
  {
    float g0 = n1g[lane], g1 = n1g[lane+64], e0 = n1b[lane], e1 = n1b[lane+64];
    for (int n = wave; n < 49; n += 16) {
      int r = n / 7, c = n - r * 7;
      int si = wi*7 + r + 3; if (si >= 56) si -= 56;
      int sj = wj*7 + c + 3; if (sj >= 56) sj -= 56;
      const float* xr = x + (b*3136 + si*56 + sj) * 128;
      float v0 = xr[lane], v1 = xr[lane + 64];
      float s = v0 + v1, sq = v0*v0 + v1*v1;
      #pragma unroll
      for (int off = 32; off > 0; off >>= 1) {
        s  += __shfl_xor(s,  off);
        sq += __shfl_xor(sq, off);
      }
      float mean = s * 0.0078125f;
      float var  = sq * 0.0078125f - mean*mean;
      float rstd = rsqrtf(var + 1e-5f);
      hbuf[n][lane]    = __float2bfloat16((v0-mean)*rstd*g0 + e0);
      hbuf[n][lane+64] = __float2bfloat16((v1-mean)*rstd*g1 + e1);
    }
  }
  __syncthreads();

  // ---- phase 2: QKV GEMM. 24 feature-tiles x 2 m-halves = 48 units, 3/wave.
  //      Tiles 0-7 = Q, 8-15 = K (vector writes to qk), 16-23 = V (scalar
  //      transpose writes to vT). 24 MFMA/wave, all D[f][m]. ----
  {
    const int t0 = wlo * 3;
    f32x4 acc[3][2] = {};                 // [ft][mt]  D[f][m], m-half mh
    #pragma unroll
    for (int ks = 0; ks < 4; ++ks) {
      short8 hf[2];
      #pragma unroll
      for (int mt = 0; mt < 2; ++mt)
        hf[mt] = *(const short8*)(&hbuf[mh*32 + mt*16 + l15][ks*32 + quad*8]);
      #pragma unroll
      for (int ft = 0; ft < 3; ++ft) {
        short8 wf = *(const short8*)(qkvwb + ((t0 + ft)*16 + l15)*128 + ks*32 + quad*8);
        #pragma unroll
        for (int mt = 0; mt < 2; ++mt)
          acc[ft][mt] = __builtin_amdgcn_mfma_f32_16x16x32_bf16(wf, hf[mt], acc[ft][mt], 0, 0, 0);
      }
    }
    #pragma unroll
    for (int ft = 0; ft < 3; ++ft) {
      const int t = t0 + ft;
      if (t < 16) {            // Q or K tile
        const int which = t >> 3;
        const int fo = (t & 7) * 16 + quad * 4;    // within-which feature
        const int hh = fo >> 5, d0 = fo & 31;
        const float qs = (t < 8) ? 0.17677669529663687f : 1.0f;
        float bb[4];
        #pragma unroll
        for (int r = 0; r < 4; ++r) bb[r] = qkvb[which*128 + fo + r];
        #pragma unroll
        for (int mt = 0; mt < 2; ++mt) {
          int m = mh*32 + mt*16 + l15;
          if (m < 49) {
            short4v pk;
            #pragma unroll
            for (int r = 0; r < 4; ++r) pk[r] = f2bs((acc[ft][mt][r] + bb[r]) * qs);
            *(short4v*)(qkb + ((hh*2 + which)*64 + m)*40 + d0) = pk;
          }
        }
      } else {                 // V tile: transpose-write into vT[h][d][m]
        const int nf = (t - 16) * 16 + quad * 4;   // V feature 0..127
        const int hh = nf >> 5, d0 = nf & 31;
        float bb[4];
        #pragma unroll
        for (int r = 0; r < 4; ++r) bb[r] = qkvb[256 + nf + r];
        #pragma unroll
        for (int mt = 0; mt < 2; ++mt) {
          int m = mh*32 + mt*16 + l15;
          #pragma unroll
          for (int r = 0; r < 4; ++r) {
            float v = (m < 49) ? (acc[ft][mt][r] + bb[r]) : 0.f;
            vT[hh][d0 + r][m] = __float2bfloat16(v);
          }
        }
      }
    }
  }
  __syncthreads();

  // ---- phase 3: attention, wave = (head, query-16-tile) ----
  {
    const int h = wave >> 2, nt = wave & 3;
    __hip_bfloat16* qbase = qkb + (h*2 + 0)*64*40;
    __hip_bfloat16* kbase = qkb + (h*2 + 1)*64*40;
    short8 kf[4], qf;
    #pragma unroll
    for (int mt = 0; mt < 4; ++mt) kf[mt] = *(const short8*)(kbase + (mt*16 + l15)*40 + quad*8);
    qf = *(const short8*)(qbase + (nt*16 + l15)*40 + quad*8);
    __syncthreads();   // all Q/K frag loads done before P overlays the region

    f32x4 sacc[4] = {};   // [mt] : m = mt*16+quad*4+r, n = nt*16+l15
    #pragma unroll
    for (int mt = 0; mt < 4; ++mt)
      sacc[mt] = __builtin_amdgcn_mfma_f32_16x16x32_bf16(kf[mt], qf, sacc[mt], 0, 0, 0);

    const float* bT = biasT + h*4096;
    #pragma unroll
    for (int mt = 0; mt < 4; ++mt)
      #pragma unroll
      for (int r = 0; r < 4; ++r)
        sacc[mt][r] += bT[(mt*16 + quad*4 + r)*64 + nt*16 + l15];

    __hip_bfloat16* pb = qbase;   // P[n][m], stride 72 (q+k region of this head)
    {
      float mx = -1e30f;
      #pragma unroll
      for (int mt = 0; mt < 3; ++mt)
        #pragma unroll
        for (int r = 0; r < 4; ++r) mx = fmaxf(mx, sacc[mt][r]);
      mx = fmaxf(mx, (quad == 0) ? sacc[3][0] : -1e30f);   // m=48 only
      mx = fmaxf(mx, __shfl_xor(mx, 16));
      mx = fmaxf(mx, __shfl_xor(mx, 32));
      float sum = 0.f;
      #pragma unroll
      for (int mt = 0; mt < 3; ++mt)
        #pragma unroll
        for (int r = 0; r < 4; ++r) {
          float e = __expf(sacc[mt][r] - mx);
          sacc[mt][r] = e; sum += e;
        }
      {
        float e = (quad == 0) ? __expf(sacc[3][0] - mx) : 0.f;
        sacc[3][0] = e; sacc[3][1] = 0.f; sacc[3][2] = 0.f; sacc[3][3] = 0.f;
        sum += e;
      }
      sum += __shfl_xor(sum, 16);
      sum += __shfl_xor(sum, 32);
      float inv = 1.f / sum;
      int n = nt*16 + l15;
      #pragma unroll
      for (int mt = 0; mt < 4; ++mt) {
        short4v pk;
        #pragma unroll
        for (int r = 0; r < 4; ++r) pk[r] = f2bs(sacc[mt][r] * inv);
        *(short4v*)(pb + n*72 + mt*16 + quad*4) = pk;
      }
    }

    // AV: A=V^T rows d, B=P rows n (own tile, written by this wave) -> D[d][n]
    f32x4 oacc[2] = {};
    #pragma unroll
    for (int kt = 0; kt < 2; ++kt) {
      short8 vf[2], pf;
      #pragma unroll
      for (int dt = 0; dt < 2; ++dt)
        vf[dt] = *(const short8*)(&vT[h][dt*16 + l15][kt*32 + quad*8]);
      pf = *(const short8*)(pb + (nt*16 + l15)*72 + kt*32 + quad*8);
      #pragma unroll
      for (int dt = 0; dt < 2; ++dt)
        oacc[dt] = __builtin_amdgcn_mfma_f32_16x16x32_bf16(vf[dt], pf, oacc[dt], 0, 0, 0);
    }
    #pragma unroll
    for (int dt = 0; dt < 2; ++dt) {
      int n = nt*16 + l15;
      if (n < 49) {
        short4v pk;
        #pragma unroll
        for (int r = 0; r < 4; ++r) pk[r] = f2bs(oacc[dt][r]);
        *(short4v*)(&hbuf[n][h*32 + dt*16 + quad*4]) = pk;
      }
    }
  }
  __syncthreads();

  // ---- phase 4: proj + shortcut -> x2 in REGISTERS (fp32) + fp32 LDS mirror.
  //      wave = (col-tile wlo, m-half mh). ----
  f32x4 x2v[2];   // [mt]: m = mh*32+mt*16+quad*4+r, f = wlo*16+l15
  {
    f32x4 acc[2] = {};
    #pragma unroll
    for (int ks = 0; ks < 4; ++ks) {
      short8 af[2];
      #pragma unroll
      for (int mt = 0; mt < 2; ++mt)
        af[mt] = *(const short8*)(&hbuf[mh*32 + mt*16 + l15][ks*32 + quad*8]);
      short8 bfr = *(const short8*)(projwb + (wlo*16 + l15)*128 + ks*32 + quad*8);
      #pragma unroll
      for (int mt = 0; mt < 2; ++mt)
        acc[mt] = __builtin_amdgcn_mfma_f32_16x16x32_bf16(af[mt], bfr, acc[mt], 0, 0, 0);
    }
    int n = wlo*16 + l15;
    float pbv = projb[n];
    #pragma unroll
    for (int mt = 0; mt < 2; ++mt) {
      #pragma unroll
      for (int r = 0; r < 4; ++r) {
        int m = mh*32 + mt*16 + quad*4 + r;
        float v = 0.f;
        if (m < 49) {
          int rr = m / 7, cc = m - rr * 7;
          int si = wi*7 + rr + 3; if (si >= 56) si -= 56;
          int sj = wj*7 + cc + 3; if (sj >= 56) sj -= 56;
          int o = (b*3136 + si*56 + sj) * 128 + n;
          v = acc[mt][r] + pbv + x[o];
        }
        x2v[mt][r] = v;
        x2s[m*132 + n] = v;     // fp32 mirror for LN2 (overlays dead Q/K/P)
      }
    }
  }
  __syncthreads();

  // ---- phase 5: LN2 from x2s -> hbuf bf16 (hbuf o-tile dead now) ----
  {
    float g0 = n2g[lane], g1 = n2g[lane+64], e0 = n2b[lane], e1 = n2b[lane+64];
    for (int n = wave; n < 49; n += 16) {
      float v0 = x2s[n*132 + lane], v1 = x2s[n*132 + lane + 64];
      float s = v0 + v1, sq = v0*v0 + v1*v1;
      #pragma unroll
      for (int off = 32; off > 0; off >>= 1) {
        s  += __shfl_xor(s,  off);
        sq += __shfl_xor(sq, off);
      }
      float mean = s * 0.0078125f;
      float var  = sq * 0.0078125f - mean*mean;
      float rstd = rsqrtf(var + 1e-5f);
      hbuf[n][lane]    = __float2bfloat16((v0-mean)*rstd*g0 + e0);
      hbuf[n][lane+64] = __float2bfloat16((v1-mean)*rstd*g1 + e1);
    }
    __hip_bfloat16 z = __float2bfloat16(0.f);
    for (int n = 49 + wave; n < 64; n += 16) {  // zero pad rows for GEMM1
      hbuf[n][lane] = z; hbuf[n][lane+64] = z;
    }
  }
  __syncthreads();   // also: x2s reads done -> region A reusable as hidden buf

  // ---- phase 6: MLP, hidden in 2 chunks of 256; GEMM2 accumulates ----
  f32x4 acc2[2] = {};   // [mt]: m = mh*32+mt*16+quad*4+r, f = wlo*16+l15
  #pragma unroll
  for (int chunk = 0; chunk < 2; ++chunk) {
    // GEMM1 chunk: wave covers j-tile [chunk*256 + wave*16, +16), D[j][m] swapped
    {
      const int jg = chunk*256 + wave*16;
      f32x4 acc1[4] = {};   // [mt]
      #pragma unroll
      for (int ks = 0; ks < 4; ++ks) {
        short8 lf[4];
        #pragma unroll
        for (int mt = 0; mt < 4; ++mt)
          lf[mt] = *(const short8*)(&hbuf[mt*16 + l15][ks*32 + quad*8]);
        short8 wf = *(const short8*)(w1b + (jg + l15)*128 + ks*32 + quad*8);
        #pragma unroll
        for (int mt = 0; mt < 4; ++mt)
          acc1[mt] = __builtin_amdgcn_mfma_f32_16x16x32_bf16(wf, lf[mt], acc1[mt], 0, 0, 0);
      }
      int j0l = wave*16 + quad*4;         // chunk-local j
      float bb[4];
      #pragma unroll
      for (int r = 0; r < 4; ++r) bb[r] = b1[chunk*256 + j0l + r];
      #pragma unroll
      for (int mt = 0; mt < 4; ++mt) {
        int m = mt*16 + l15;
        short4v pk;
        #pragma unroll
        for (int r = 0; r < 4; ++r) pk[r] = f2bs(gelu_f(acc1[mt][r] + bb[r]));
        *(short4v*)(hb + m*264 + j0l) = pk;
      }
    }
    __syncthreads();   // hb chunk ready

    // GEMM2 partial: k in [chunk*256, +256), D[m][f]; wave = (f-tile wlo, m-half mh)
    {
      #pragma unroll
      for (int ks = 0; ks < 8; ++ks) {
        short8 af[2];
        #pragma unroll
        for (int mt = 0; mt < 2; ++mt)
          af[mt] = *(const short8*)(hb + (mh*32 + mt*16 + l15)*264 + ks*32 + quad*8);
        short8 bfr = *(const short8*)(w2b + (wlo*16 + l15)*512 + chunk*256 + ks*32 + quad*8);
        #pragma unroll
        for (int mt = 0; mt < 2; ++mt)
          acc2[mt] = __builtin_amdgcn_mfma_f32_16x16x32_bf16(af[mt], bfr, acc2[mt], 0, 0, 0);
      }
    }
    if (chunk == 0) __syncthreads();   // hb consumed, safe to overwrite
  }

  // ---- epilogue: bias + register residual, scatter (roll +3) ----
  {
    const int f = wlo*16 + l15;
    const float bb = b2[f];
    #pragma unroll
    for (int mt = 0; mt < 2; ++mt) {
      #pragma unroll
      for (int r = 0; r < 4; ++r) {
        int m = mh*32 + mt*16 + quad*4 + r;
        if (m < 49) {
          int rr = m / 7, cc = m - rr * 7;
          int si = wi*7 + rr + 3; if (si >= 56) si -= 56;
          int sj = wj*7 + cc + 3; if (sj >= 56) sj -= 56;
          int o = (b*3136 + si*56 + sj) * 128 + f;
          out[o] = acc2[mt][r] + bb + x2v[mt][r];
        }
      }
    }
  }
}

extern "C" void kernel_launch(void* const* d_in, const int* in_sizes, int n_in,
                              void* d_out, int out_size, void* d_ws, size_t ws_size,
                              hipStream_t stream) {
  const float* x     = (const float*)d_in[0];
  const float* n1g   = (const float*)d_in[3];
  const float* n1b   = (const float*)d_in[4];
  const float* qkvw  = (const float*)d_in[5];
  const float* qkvb  = (const float*)d_in[6];
  const float* tab   = (const float*)d_in[7];
  const int*   ridx  = (const int*)d_in[8];
  const float* projw = (const float*)d_in[9];
  const float* projb = (const float*)d_in[10];
  const float* n2g   = (const float*)d_in[11];
  const float* n2b   = (const float*)d_in[12];
  const float* w1    = (const float*)d_in[13];
  const float* b1    = (const float*)d_in[14];
  const float* w2    = (const float*)d_in[15];
  const float* b2    = (const float*)d_in[16];
  float* outp = (float*)d_out;

  __hip_bfloat16* wsb = (__hip_bfloat16*)d_ws;
  float* biasT = (float*)((char*)d_ws + BIAS_BYTE_OFF);

  hipLaunchKernelGGL(conv_kernel, dim3(832), dim3(256), 0, stream,
                     qkvw, projw, w1, w2, tab, ridx, wsb, biasT);
  hipLaunchKernelGGL(fused_kernel, dim3(NWIN), dim3(1024), 0, stream,
                     x, n1g, n1b, wsb + QKVW_OFF, qkvb, biasT, wsb + PROJW_OFF, projb,
                     n2g, n2b, wsb + W1_OFF, b1, wsb + W2_OFF, b2, outp);
}

// Round 4
// 262.050 us; speedup vs baseline: 1.3186x; 1.3186x over previous
//
#include <hip/hip_runtime.h>
#include <hip/hip_bf16.h>

// Swin block, B=32 H=W=56 C=128, ws=7 (N=49), nh=4 (hd=32), shift=3, hid=512.
// fp32 in/out. All GEMMs AND attention (QK^T, AV) via mfma_f32_16x16x32_bf16.
// roll(-3) gather == roll(+3) scatter target -> fully fused windows.
// R9: revert R8's 1024-thread config (VGPR_Count=32 + 3.6x HBM traffic =
//     scratch spills; 253us). Back to R7 (512 thr, 8 waves, 64 VGPR, 175us)
//     + three latency hoists using the idle VGPR headroom (budget 128):
//     (1) LN1 issues all row loads up-front (was serial load->reduce chain),
//     (2) phase-3 biasT loads hoisted before the mid barrier (drain absorbs),
//     (3) phase-4 residual x[o] loads hoisted before the proj MFMA loop.

#define NWIN 2048

typedef short short8  __attribute__((ext_vector_type(8)));
typedef short short4v __attribute__((ext_vector_type(4)));
typedef float f32x4   __attribute__((ext_vector_type(4)));

#define QKVW_OFF  0        // 384*128 bf16
#define PROJW_OFF 49152    // 128*128
#define W1_OFF    65536    // 512*128
#define W2_OFF    131072   // 128*512
#define BIAS_BYTE_OFF 393216  // biasT[4][64][64] fp32 (padded, 0 outside 49x49)

__device__ __forceinline__ short f2bs(float v) {
  __hip_bfloat16 h = __float2bfloat16(v);
  union { __hip_bfloat16 h; short s; } u; u.h = h; return u.s;
}
__device__ __forceinline__ float gelu_f(float v) {
  float u = v * (0.7978845608028654f + 0.03567740814f * v * v);
  return v * __builtin_amdgcn_rcpf(1.f + __expf(-2.f * u));
}

// ---------------- pre-pass: weights -> bf16, padded bias^T gather ----------------
__global__ __launch_bounds__(256) void conv_kernel(
    const float* __restrict__ qkvw, const float* __restrict__ projw,
    const float* __restrict__ w1,   const float* __restrict__ w2,
    const float* __restrict__ tab,  const int* __restrict__ ridx,
    __hip_bfloat16* __restrict__ wsb, float* __restrict__ biasT)
{
  int idx = blockIdx.x * 256 + threadIdx.x;
  if (idx < 49152)       wsb[QKVW_OFF + idx]          = __float2bfloat16(qkvw[idx]);
  else if (idx < 65536)  wsb[PROJW_OFF + idx - 49152] = __float2bfloat16(projw[idx - 49152]);
  else if (idx < 131072) wsb[W1_OFF + idx - 65536]    = __float2bfloat16(w1[idx - 65536]);
  else if (idx < 196608) wsb[W2_OFF + idx - 131072]   = __float2bfloat16(w2[idx - 131072]);
  else if (idx < 212992) {
    int i = idx - 196608;
    int h = i >> 12, m = (i >> 6) & 63, n = i & 63;   // biasT[h][m=key][n=query]
    biasT[i] = (m < 49 && n < 49) ? tab[ridx[n*49 + m]*4 + h] : 0.f;
  }
}

// ------- fused: LN1 + window attn + proj + shortcut + LN2 + MLP + residual -------
__global__ __launch_bounds__(512, 4) void fused_kernel(
    const float* __restrict__ x,
    const float* __restrict__ n1g, const float* __restrict__ n1b,
    const __hip_bfloat16* __restrict__ qkvwb, const float* __restrict__ qkvb,
    const float* __restrict__ biasT,
    const __hip_bfloat16* __restrict__ projwb, const float* __restrict__ projb,
    const float* __restrict__ n2g, const float* __restrict__ n2b,
    const __hip_bfloat16* __restrict__ w1b, const float* __restrict__ b1,
    const __hip_bfloat16* __restrict__ w2b, const float* __restrict__ b2,
    float* __restrict__ out)
{
  __shared__ alignas(16) __hip_bfloat16 hbuf[64][136];   // 17408 B: h / o / ln2
  __shared__ alignas(16) char regA[40960];               // qk | x2s fp32 | hidden
  __shared__ alignas(16) __hip_bfloat16 vT[4][32][72];   // 18432 B
  __hip_bfloat16* const qkb = (__hip_bfloat16*)regA;     // qk[4][2][64][40]
  float*          const x2s = (float*)regA;              // [64][132] fp32 (33792 B)
  __hip_bfloat16* const hb  = (__hip_bfloat16*)regA;     // [64][264] (33792 B)

  const int tid = threadIdx.x, wave = tid >> 6, lane = tid & 63;
  const int l15 = lane & 15, quad = lane >> 4;
  const int b = blockIdx.x >> 6, wi = (blockIdx.x >> 3) & 7, wj = blockIdx.x & 7;

  // ---- phase 1: LN1 over source rows (roll -3) -> hbuf bf16.
  //      All global loads issued up-front, then independent reduce chains. ----
  {
    float g0 = n1g[lane], g1 = n1g[lane+64], e0 = n1b[lane], e1 = n1b[lane+64];
    float va[7], vb[7];
    #pragma unroll
    for (int i = 0; i < 7; ++i) {
      int n = wave + i*8;
      va[i] = 0.f; vb[i] = 0.f;
      if (n < 49) {
        int r = n / 7, c = n - r * 7;
        int si = wi*7 + r + 3; if (si >= 56) si -= 56;
        int sj = wj*7 + c + 3; if (sj >= 56) sj -= 56;
        const float* xr = x + (b*3136 + si*56 + sj) * 128;
        va[i] = xr[lane]; vb[i] = xr[lane + 64];
      }
    }
    #pragma unroll
    for (int i = 0; i < 7; ++i) {
      int n = wave + i*8;
      if (n < 49) {
        float s = va[i] + vb[i], sq = va[i]*va[i] + vb[i]*vb[i];
        #pragma unroll
        for (int off = 32; off > 0; off >>= 1) {
          s  += __shfl_xor(s,  off);
          sq += __shfl_xor(sq, off);
        }
        float mean = s * 0.0078125f;
        float var  = sq * 0.0078125f - mean*mean;
        float rstd = rsqrtf(var + 1e-5f);
        hbuf[n][lane]    = __float2bfloat16((va[i]-mean)*rstd*g0 + e0);
        hbuf[n][lane+64] = __float2bfloat16((vb[i]-mean)*rstd*g1 + e1);
      }
    }
  }
  __syncthreads();

  // ---- phase 2: QKV GEMM. 24 tiles of 16 features, 3 per wave, all D[f][m].
  //      Tiles 0-7 = Q, 8-15 = K (vector writes to qk), 16-23 = V (scalar
  //      transpose writes to vT). 48 MFMA/wave. ----
  {
    const int t0 = wave * 3;
    f32x4 acc[3][4] = {};                 // [ft][mt]  D[f][m]
    #pragma unroll
    for (int ks = 0; ks < 4; ++ks) {
      short8 hf[4];
      #pragma unroll
      for (int mt = 0; mt < 4; ++mt)
        hf[mt] = *(const short8*)(&hbuf[mt*16 + l15][ks*32 + quad*8]);
      #pragma unroll
      for (int ft = 0; ft < 3; ++ft) {
        short8 wf = *(const short8*)(qkvwb + ((t0 + ft)*16 + l15)*128 + ks*32 + quad*8);
        #pragma unroll
        for (int mt = 0; mt < 4; ++mt)
          acc[ft][mt] = __builtin_amdgcn_mfma_f32_16x16x32_bf16(wf, hf[mt], acc[ft][mt], 0, 0, 0);
      }
    }
    #pragma unroll
    for (int ft = 0; ft < 3; ++ft) {
      const int t = t0 + ft;
      if (t < 16) {            // Q or K tile
        const int which = t >> 3;
        const int fo = (t & 7) * 16 + quad * 4;    // within-which feature
        const int hh = fo >> 5, d0 = fo & 31;
        const float qs = (t < 8) ? 0.17677669529663687f : 1.0f;
        float bb[4];
        #pragma unroll
        for (int r = 0; r < 4; ++r) bb[r] = qkvb[which*128 + fo + r];
        #pragma unroll
        for (int mt = 0; mt < 4; ++mt) {
          int m = mt*16 + l15;
          if (m < 49) {
            short4v pk;
            #pragma unroll
            for (int r = 0; r < 4; ++r) pk[r] = f2bs((acc[ft][mt][r] + bb[r]) * qs);
            *(short4v*)(qkb + ((hh*2 + which)*64 + m)*40 + d0) = pk;
          }
        }
      } else {                 // V tile: transpose-write into vT[h][d][m]
        const int nf = (t - 16) * 16 + quad * 4;   // V feature 0..127
        const int hh = nf >> 5, d0 = nf & 31;
        float bb[4];
        #pragma unroll
        for (int r = 0; r < 4; ++r) bb[r] = qkvb[256 + nf + r];
        #pragma unroll
        for (int mt = 0; mt < 4; ++mt) {
          int m = mt*16 + l15;
          #pragma unroll
          for (int r = 0; r < 4; ++r) {
            float v = (m < 49) ? (acc[ft][mt][r] + bb[r]) : 0.f;
            vT[hh][d0 + r][m] = __float2bfloat16(v);
          }
        }
      }
    }
  }
  __syncthreads();

  // ---- phase 3: attention, 2 waves per head (query-half split) ----
  {
    const int h = wave >> 1, half = wave & 1;
    __hip_bfloat16* qbase = qkb + (h*2 + 0)*64*40;
    __hip_bfloat16* kbase = qkb + (h*2 + 1)*64*40;
    short8 kf[4], qf[2];
    #pragma unroll
    for (int mt = 0; mt < 4; ++mt) kf[mt] = *(const short8*)(kbase + (mt*16 + l15)*40 + quad*8);
    #pragma unroll
    for (int nt = 0; nt < 2; ++nt)
      qf[nt] = *(const short8*)(qbase + ((half*2 + nt)*16 + l15)*40 + quad*8);
    // hoisted biasT loads: in flight across the barrier (drain absorbs latency)
    const float* bT = biasT + h*4096;
    float bv[4][2][4];
    #pragma unroll
    for (int mt = 0; mt < 4; ++mt)
      #pragma unroll
      for (int nt = 0; nt < 2; ++nt)
        #pragma unroll
        for (int r = 0; r < 4; ++r)
          bv[mt][nt][r] = bT[(mt*16 + quad*4 + r)*64 + (half*2 + nt)*16 + l15];
    __syncthreads();   // all Q/K frag loads done before P overlays the region

    f32x4 sacc[4][2] = {};   // [mt][nt] : m = mt*16+quad*4+r, n = (half*2+nt)*16+l15
    #pragma unroll
    for (int mt = 0; mt < 4; ++mt)
      #pragma unroll
      for (int nt = 0; nt < 2; ++nt)
        sacc[mt][nt] = __builtin_amdgcn_mfma_f32_16x16x32_bf16(kf[mt], qf[nt], sacc[mt][nt], 0, 0, 0);

    #pragma unroll
    for (int mt = 0; mt < 4; ++mt)
      #pragma unroll
      for (int nt = 0; nt < 2; ++nt)
        #pragma unroll
        for (int r = 0; r < 4; ++r)
          sacc[mt][nt][r] += bv[mt][nt][r];

    __hip_bfloat16* pb = qbase;   // P[n][m], stride 72 (q+k region of this head)
    #pragma unroll
    for (int nt = 0; nt < 2; ++nt) {
      float mx = -1e30f;
      #pragma unroll
      for (int mt = 0; mt < 3; ++mt)
        #pragma unroll
        for (int r = 0; r < 4; ++r) mx = fmaxf(mx, sacc[mt][nt][r]);
      mx = fmaxf(mx, (quad == 0) ? sacc[3][nt][0] : -1e30f);   // m=48 only
      mx = fmaxf(mx, __shfl_xor(mx, 16));
      mx = fmaxf(mx, __shfl_xor(mx, 32));
      float sum = 0.f;
      #pragma unroll
      for (int mt = 0; mt < 3; ++mt)
        #pragma unroll
        for (int r = 0; r < 4; ++r) {
          float e = __expf(sacc[mt][nt][r] - mx);
          sacc[mt][nt][r] = e; sum += e;
        }
      {
        float e = (quad == 0) ? __expf(sacc[3][nt][0] - mx) : 0.f;
        sacc[3][nt][0] = e; sacc[3][nt][1] = 0.f; sacc[3][nt][2] = 0.f; sacc[3][nt][3] = 0.f;
        sum += e;
      }
      sum += __shfl_xor(sum, 16);
      sum += __shfl_xor(sum, 32);
      float inv = 1.f / sum;
      int n = (half*2 + nt)*16 + l15;
      #pragma unroll
      for (int mt = 0; mt < 4; ++mt) {
        short4v pk;
        #pragma unroll
        for (int r = 0; r < 4; ++r) pk[r] = f2bs(sacc[mt][nt][r] * inv);
        *(short4v*)(pb + n*72 + mt*16 + quad*4) = pk;
      }
    }

    // AV: A=V^T rows d, B=P rows n (own half) -> D[d][n]
    f32x4 oacc[2][2] = {};
    #pragma unroll
    for (int kt = 0; kt < 2; ++kt) {
      short8 vf[2], pf[2];
      #pragma unroll
      for (int dt = 0; dt < 2; ++dt)
        vf[dt] = *(const short8*)(&vT[h][dt*16 + l15][kt*32 + quad*8]);
      #pragma unroll
      for (int nc = 0; nc < 2; ++nc)
        pf[nc] = *(const short8*)(pb + ((half*2 + nc)*16 + l15)*72 + kt*32 + quad*8);
      #pragma unroll
      for (int dt = 0; dt < 2; ++dt)
        #pragma unroll
        for (int nc = 0; nc < 2; ++nc)
          oacc[dt][nc] = __builtin_amdgcn_mfma_f32_16x16x32_bf16(vf[dt], pf[nc], oacc[dt][nc], 0, 0, 0);
    }
    #pragma unroll
    for (int dt = 0; dt < 2; ++dt)
      #pragma unroll
      for (int nc = 0; nc < 2; ++nc) {
        int n = (half*2 + nc)*16 + l15;
        if (n < 49) {
          short4v pk;
          #pragma unroll
          for (int r = 0; r < 4; ++r) pk[r] = f2bs(oacc[dt][nc][r]);
          *(short4v*)(&hbuf[n][h*32 + dt*16 + quad*4]) = pk;
        }
      }
  }
  __syncthreads();

  // ---- phase 4: proj + shortcut -> x2 in REGISTERS (fp32) + fp32 LDS mirror.
  //      Residual x[o] loads issued BEFORE the MFMA loop (latency hidden). ----
  f32x4 x2v[4];   // [mt]: m = mt*16+quad*4+r, f = wave*16+l15
  {
    const int ncol0 = wave * 16;
    const int n = ncol0 + l15;
    float xres[4][4];
    #pragma unroll
    for (int mt = 0; mt < 4; ++mt) {
      #pragma unroll
      for (int r = 0; r < 4; ++r) {
        int m = mt*16 + quad*4 + r;
        float v = 0.f;
        if (m < 49) {
          int rr = m / 7, cc = m - rr * 7;
          int si = wi*7 + rr + 3; if (si >= 56) si -= 56;
          int sj = wj*7 + cc + 3; if (sj >= 56) sj -= 56;
          v = x[(b*3136 + si*56 + sj) * 128 + n];
        }
        xres[mt][r] = v;
      }
    }
    f32x4 acc[4] = {};
    #pragma unroll
    for (int ks = 0; ks < 4; ++ks) {
      short8 af[4];
      #pragma unroll
      for (int mt = 0; mt < 4; ++mt)
        af[mt] = *(const short8*)(&hbuf[mt*16 + l15][ks*32 + quad*8]);
      short8 bfr = *(const short8*)(projwb + (ncol0 + l15)*128 + ks*32 + quad*8);
      #pragma unroll
      for (int mt = 0; mt < 4; ++mt)
        acc[mt] = __builtin_amdgcn_mfma_f32_16x16x32_bf16(af[mt], bfr, acc[mt], 0, 0, 0);
    }
    float pbv = projb[n];
    #pragma unroll
    for (int mt = 0; mt < 4; ++mt) {
      #pragma unroll
      for (int r = 0; r < 4; ++r) {
        int m = mt*16 + quad*4 + r;
        float v = 0.f;
        if (m < 49) v = acc[mt][r] + pbv + xres[mt][r];
        x2v[mt][r] = v;
        x2s[m*132 + n] = v;     // fp32 mirror for LN2 (overlays dead Q/K/P)
      }
    }
  }
  __syncthreads();

  // ---- phase 5: LN2 from x2s -> hbuf bf16 (hbuf o-tile dead now) ----
  {
    float g0 = n2g[lane], g1 = n2g[lane+64], e0 = n2b[lane], e1 = n2b[lane+64];
    for (int n = wave; n < 49; n += 8) {
      float v0 = x2s[n*132 + lane], v1 = x2s[n*132 + lane + 64];
      float s = v0 + v1, sq = v0*v0 + v1*v1;
      #pragma unroll
      for (int off = 32; off > 0; off >>= 1) {
        s  += __shfl_xor(s,  off);
        sq += __shfl_xor(sq, off);
      }
      float mean = s * 0.0078125f;
      float var  = sq * 0.0078125f - mean*mean;
      float rstd = rsqrtf(var + 1e-5f);
      hbuf[n][lane]    = __float2bfloat16((v0-mean)*rstd*g0 + e0);
      hbuf[n][lane+64] = __float2bfloat16((v1-mean)*rstd*g1 + e1);
    }
    __hip_bfloat16 z = __float2bfloat16(0.f);
    for (int n = 49 + wave; n < 64; n += 8) {   // zero pad rows for GEMM1
      hbuf[n][lane] = z; hbuf[n][lane+64] = z;
    }
  }
  __syncthreads();   // also: x2s reads done -> region A reusable as hidden buf

  // ---- phase 6: MLP, hidden in 2 chunks of 256; GEMM2 accumulates ----
  f32x4 acc2[4] = {};   // [mt]: m = mt*16+quad*4+r, f = wave*16+l15
  #pragma unroll
  for (int chunk = 0; chunk < 2; ++chunk) {
    // GEMM1 chunk: wave covers j in [chunk*256 + wave*32, +32), D[j][m] swapped
    {
      const int jbl = wave * 32;
      f32x4 acc1[2][4] = {};   // [jt][mt]
      #pragma unroll
      for (int ks = 0; ks < 4; ++ks) {
        short8 lf[4];
        #pragma unroll
        for (int mt = 0; mt < 4; ++mt)
          lf[mt] = *(const short8*)(&hbuf[mt*16 + l15][ks*32 + quad*8]);
        #pragma unroll
        for (int jt = 0; jt < 2; ++jt) {
          short8 wf = *(const short8*)(w1b + (chunk*256 + jbl + jt*16 + l15)*128 + ks*32 + quad*8);
          #pragma unroll
          for (int mt = 0; mt < 4; ++mt)
            acc1[jt][mt] = __builtin_amdgcn_mfma_f32_16x16x32_bf16(wf, lf[mt], acc1[jt][mt], 0, 0, 0);
        }
      }
      #pragma unroll
      for (int jt = 0; jt < 2; ++jt) {
        int j0l = jbl + jt*16 + quad*4;         // chunk-local j
        float bb[4];
        #pragma unroll
        for (int r = 0; r < 4; ++r) bb[r] = b1[chunk*256 + j0l + r];
        #pragma unroll
        for (int mt = 0; mt < 4; ++mt) {
          int m = mt*16 + l15;
          short4v pk;
          #pragma unroll
          for (int r = 0; r < 4; ++r) pk[r] = f2bs(gelu_f(acc1[jt][mt][r] + bb[r]));
          *(short4v*)(hb + m*264 + j0l) = pk;
        }
      }
    }
    __syncthreads();   // hb chunk ready

    // GEMM2 partial: k in [chunk*256, +256), D[m][f]; wave covers f in [wave*16, +16)
    {
      const int fb2 = wave * 16;
      #pragma unroll
      for (int ks = 0; ks < 8; ++ks) {
        short8 af[4];
        #pragma unroll
        for (int mt = 0; mt < 4; ++mt)
          af[mt] = *(const short8*)(hb + (mt*16 + l15)*264 + ks*32 + quad*8);
        short8 bfr = *(const short8*)(w2b + (fb2 + l15)*512 + chunk*256 + ks*32 + quad*8);
        #pragma unroll
        for (int mt = 0; mt < 4; ++mt)
          acc2[mt] = __builtin_amdgcn_mfma_f32_16x16x32_bf16(af[mt], bfr, acc2[mt], 0, 0, 0);
      }
    }
    if (chunk == 0) __syncthreads();   // hb consumed, safe to overwrite
  }

  // ---- epilogue: bias + register residual, scatter (roll +3) ----
  {
    const int f = wave * 16 + l15;
    const float bb = b2[f];
    #pragma unroll
    for (int mt = 0; mt < 4; ++mt) {
      #pragma unroll
      for (int r = 0; r < 4; ++r) {
        int m = mt*16 + quad*4 + r;
        if (m < 49) {
          int rr = m / 7, cc = m - rr * 7;
          int si = wi*7 + rr + 3; if (si >= 56) si -= 56;
          int sj = wj*7 + cc + 3; if (sj >= 56) sj -= 56;
          int o = (b*3136 + si*56 + sj) * 128 + f;
          out[o] = acc2[mt][r] + bb + x2v[mt][r];
        }
      }
    }
  }
}

extern "C" void kernel_launch(void* const* d_in, const int* in_sizes, int n_in,
                              void* d_out, int out_size, void* d_ws, size_t ws_size,
                              hipStream_t stream) {
  const float* x     = (const float*)d_in[0];
  const float* n1g   = (const float*)d_in[3];
  const float* n1b   = (const float*)d_in[4];
  const float* qkvw  = (const float*)d_in[5];
  const float* qkvb  = (const float*)d_in[6];
  const float* tab   = (const float*)d_in[7];
  const int*   ridx  = (const int*)d_in[8];
  const float* projw = (const float*)d_in[9];
  const float* projb = (const float*)d_in[10];
  const float* n2g   = (const float*)d_in[11];
  const float* n2b   = (const float*)d_in[12];
  const float* w1    = (const float*)d_in[13];
  const float* b1    = (const float*)d_in[14];
  const float* w2    = (const float*)d_in[15];
  const float* b2    = (const float*)d_in[16];
  float* outp = (float*)d_out;

  __hip_bfloat16* wsb = (__hip_bfloat16*)d_ws;
  float* biasT = (float*)((char*)d_ws + BIAS_BYTE_OFF);

  hipLaunchKernelGGL(conv_kernel, dim3(832), dim3(256), 0, stream,
                     qkvw, projw, w1, w2, tab, ridx, wsb, biasT);
  hipLaunchKernelGGL(fused_kernel, dim3(NWIN), dim3(512), 0, stream,
                     x, n1g, n1b, wsb + QKVW_OFF, qkvb, biasT, wsb + PROJW_OFF, projb,
                     n2g, n2b, wsb + W1_OFF, b1, wsb + W2_OFF, b2, outp);
}

// Round 5
// 257.352 us; speedup vs baseline: 1.3427x; 1.0183x over previous
//
#include <hip/hip_runtime.h>
#include <hip/hip_bf16.h>

// Swin block, B=32 H=W=56 C=128, ws=7 (N=49), nh=4 (hd=32), shift=3, hid=512.
// fp32 in/out. All GEMMs AND attention (QK^T, AV) via mfma_f32_16x16x32_bf16.
// roll(-3) gather == roll(+3) scatter target -> fully fused windows.
// R10: R9 + systematic weight-fragment prefetch into the 64-VGPR headroom
//     ((512,4) budget = 128). All global loads that a phase consumes right
//     after a barrier are issued BEFORE that barrier (compiler can't move
//     loads across __syncthreads): qkv wfrags at kernel entry (under LN1),
//     proj wfrags + residual x rows at p3 end, w1-c0 before p5-end barrier,
//     w2-cN after each GEMM1 epilogue. p6 chunk loop manually unrolled.
//     Bank-conflict audit: b128 reads are at the 8-cycle minimum (addr ==
//     4*(l15+quad) dw covers all 32 banks x8) -- conflicts are NOT the lever.

#define NWIN 2048

typedef short short8  __attribute__((ext_vector_type(8)));
typedef short short4v __attribute__((ext_vector_type(4)));
typedef float f32x4   __attribute__((ext_vector_type(4)));

#define QKVW_OFF  0        // 384*128 bf16
#define PROJW_OFF 49152    // 128*128
#define W1_OFF    65536    // 512*128
#define W2_OFF    131072   // 128*512
#define BIAS_BYTE_OFF 393216  // biasT[4][64][64] fp32 (padded, 0 outside 49x49)

__device__ __forceinline__ short f2bs(float v) {
  __hip_bfloat16 h = __float2bfloat16(v);
  union { __hip_bfloat16 h; short s; } u; u.h = h; return u.s;
}
__device__ __forceinline__ float gelu_f(float v) {
  float u = v * (0.7978845608028654f + 0.03567740814f * v * v);
  return v * __builtin_amdgcn_rcpf(1.f + __expf(-2.f * u));
}

// ---------------- pre-pass: weights -> bf16, padded bias^T gather ----------------
__global__ __launch_bounds__(256) void conv_kernel(
    const float* __restrict__ qkvw, const float* __restrict__ projw,
    const float* __restrict__ w1,   const float* __restrict__ w2,
    const float* __restrict__ tab,  const int* __restrict__ ridx,
    __hip_bfloat16* __restrict__ wsb, float* __restrict__ biasT)
{
  int idx = blockIdx.x * 256 + threadIdx.x;
  if (idx < 49152)       wsb[QKVW_OFF + idx]          = __float2bfloat16(qkvw[idx]);
  else if (idx < 65536)  wsb[PROJW_OFF + idx - 49152] = __float2bfloat16(projw[idx - 49152]);
  else if (idx < 131072) wsb[W1_OFF + idx - 65536]    = __float2bfloat16(w1[idx - 65536]);
  else if (idx < 196608) wsb[W2_OFF + idx - 131072]   = __float2bfloat16(w2[idx - 131072]);
  else if (idx < 212992) {
    int i = idx - 196608;
    int h = i >> 12, m = (i >> 6) & 63, n = i & 63;   // biasT[h][m=key][n=query]
    biasT[i] = (m < 49 && n < 49) ? tab[ridx[n*49 + m]*4 + h] : 0.f;
  }
}

// ------- fused: LN1 + window attn + proj + shortcut + LN2 + MLP + residual -------
__global__ __launch_bounds__(512, 4) void fused_kernel(
    const float* __restrict__ x,
    const float* __restrict__ n1g, const float* __restrict__ n1b,
    const __hip_bfloat16* __restrict__ qkvwb, const float* __restrict__ qkvb,
    const float* __restrict__ biasT,
    const __hip_bfloat16* __restrict__ projwb, const float* __restrict__ projb,
    const float* __restrict__ n2g, const float* __restrict__ n2b,
    const __hip_bfloat16* __restrict__ w1b, const float* __restrict__ b1,
    const __hip_bfloat16* __restrict__ w2b, const float* __restrict__ b2,
    float* __restrict__ out)
{
  __shared__ alignas(16) __hip_bfloat16 hbuf[64][136];   // 17408 B: h / o / ln2
  __shared__ alignas(16) char regA[40960];               // qk | x2s fp32 | hidden
  __shared__ alignas(16) __hip_bfloat16 vT[4][32][72];   // 18432 B
  __hip_bfloat16* const qkb = (__hip_bfloat16*)regA;     // qk[4][2][64][40]
  float*          const x2s = (float*)regA;              // [64][132] fp32 (33792 B)
  __hip_bfloat16* const hb  = (__hip_bfloat16*)regA;     // [64][264] (33792 B)

  const int tid = threadIdx.x, wave = tid >> 6, lane = tid & 63;
  const int l15 = lane & 15, quad = lane >> 4;
  const int b = blockIdx.x >> 6, wi = (blockIdx.x >> 3) & 7, wj = blockIdx.x & 7;

  // ---- prefetch: QKV weight fragments for phase 2 (hidden under LN1) ----
  short8 wreg[3][4];
  {
    const int t0 = wave * 3;
    #pragma unroll
    for (int ft = 0; ft < 3; ++ft)
      #pragma unroll
      for (int ks = 0; ks < 4; ++ks)
        wreg[ft][ks] = *(const short8*)(qkvwb + ((t0 + ft)*16 + l15)*128 + ks*32 + quad*8);
  }

  // ---- phase 1: LN1 over source rows (roll -3) -> hbuf bf16.
  //      All global loads issued up-front, then independent reduce chains. ----
  {
    float g0 = n1g[lane], g1 = n1g[lane+64], e0 = n1b[lane], e1 = n1b[lane+64];
    float va[7], vb[7];
    #pragma unroll
    for (int i = 0; i < 7; ++i) {
      int n = wave + i*8;
      va[i] = 0.f; vb[i] = 0.f;
      if (n < 49) {
        int r = n / 7, c = n - r * 7;
        int si = wi*7 + r + 3; if (si >= 56) si -= 56;
        int sj = wj*7 + c + 3; if (sj >= 56) sj -= 56;
        const float* xr = x + (b*3136 + si*56 + sj) * 128;
        va[i] = xr[lane]; vb[i] = xr[lane + 64];
      }
    }
    #pragma unroll
    for (int i = 0; i < 7; ++i) {
      int n = wave + i*8;
      if (n < 49) {
        float s = va[i] + vb[i], sq = va[i]*va[i] + vb[i]*vb[i];
        #pragma unroll
        for (int off = 32; off > 0; off >>= 1) {
          s  += __shfl_xor(s,  off);
          sq += __shfl_xor(sq, off);
        }
        float mean = s * 0.0078125f;
        float var  = sq * 0.0078125f - mean*mean;
        float rstd = rsqrtf(var + 1e-5f);
        hbuf[n][lane]    = __float2bfloat16((va[i]-mean)*rstd*g0 + e0);
        hbuf[n][lane+64] = __float2bfloat16((vb[i]-mean)*rstd*g1 + e1);
      }
    }
  }
  __syncthreads();

  // ---- phase 2: QKV GEMM. 24 tiles of 16 features, 3 per wave, all D[f][m].
  //      Tiles 0-7 = Q, 8-15 = K (vector writes to qk), 16-23 = V (scalar
  //      transpose writes to vT). Weights from prefetched wreg. ----
  {
    const int t0 = wave * 3;
    f32x4 acc[3][4] = {};                 // [ft][mt]  D[f][m]
    #pragma unroll
    for (int ks = 0; ks < 4; ++ks) {
      short8 hf[4];
      #pragma unroll
      for (int mt = 0; mt < 4; ++mt)
        hf[mt] = *(const short8*)(&hbuf[mt*16 + l15][ks*32 + quad*8]);
      #pragma unroll
      for (int ft = 0; ft < 3; ++ft) {
        #pragma unroll
        for (int mt = 0; mt < 4; ++mt)
          acc[ft][mt] = __builtin_amdgcn_mfma_f32_16x16x32_bf16(wreg[ft][ks], hf[mt], acc[ft][mt], 0, 0, 0);
      }
    }
    #pragma unroll
    for (int ft = 0; ft < 3; ++ft) {
      const int t = t0 + ft;
      if (t < 16) {            // Q or K tile
        const int which = t >> 3;
        const int fo = (t & 7) * 16 + quad * 4;    // within-which feature
        const int hh = fo >> 5, d0 = fo & 31;
        const float qs = (t < 8) ? 0.17677669529663687f : 1.0f;
        float bb[4];
        #pragma unroll
        for (int r = 0; r < 4; ++r) bb[r] = qkvb[which*128 + fo + r];
        #pragma unroll
        for (int mt = 0; mt < 4; ++mt) {
          int m = mt*16 + l15;
          if (m < 49) {
            short4v pk;
            #pragma unroll
            for (int r = 0; r < 4; ++r) pk[r] = f2bs((acc[ft][mt][r] + bb[r]) * qs);
            *(short4v*)(qkb + ((hh*2 + which)*64 + m)*40 + d0) = pk;
          }
        }
      } else {                 // V tile: transpose-write into vT[h][d][m]
        const int nf = (t - 16) * 16 + quad * 4;   // V feature 0..127
        const int hh = nf >> 5, d0 = nf & 31;
        float bb[4];
        #pragma unroll
        for (int r = 0; r < 4; ++r) bb[r] = qkvb[256 + nf + r];
        #pragma unroll
        for (int mt = 0; mt < 4; ++mt) {
          int m = mt*16 + l15;
          #pragma unroll
          for (int r = 0; r < 4; ++r) {
            float v = (m < 49) ? (acc[ft][mt][r] + bb[r]) : 0.f;
            vT[hh][d0 + r][m] = __float2bfloat16(v);
          }
        }
      }
    }
  }
  __syncthreads();

  // ---- phase 3: attention, 2 waves per head (query-half split) ----
  short8 pw[4];        // proj weight frags (prefetched at p3 end)
  float xres[4][4];    // residual x rows (prefetched at p3 end)
  {
    const int h = wave >> 1, half = wave & 1;
    __hip_bfloat16* qbase = qkb + (h*2 + 0)*64*40;
    __hip_bfloat16* kbase = qkb + (h*2 + 1)*64*40;
    short8 kf[4], qf[2];
    #pragma unroll
    for (int mt = 0; mt < 4; ++mt) kf[mt] = *(const short8*)(kbase + (mt*16 + l15)*40 + quad*8);
    #pragma unroll
    for (int nt = 0; nt < 2; ++nt)
      qf[nt] = *(const short8*)(qbase + ((half*2 + nt)*16 + l15)*40 + quad*8);
    // hoisted biasT loads: in flight across the barrier (drain absorbs latency)
    const float* bT = biasT + h*4096;
    float bv[4][2][4];
    #pragma unroll
    for (int mt = 0; mt < 4; ++mt)
      #pragma unroll
      for (int nt = 0; nt < 2; ++nt)
        #pragma unroll
        for (int r = 0; r < 4; ++r)
          bv[mt][nt][r] = bT[(mt*16 + quad*4 + r)*64 + (half*2 + nt)*16 + l15];
    __syncthreads();   // all Q/K frag loads done before P overlays the region

    f32x4 sacc[4][2] = {};   // [mt][nt] : m = mt*16+quad*4+r, n = (half*2+nt)*16+l15
    #pragma unroll
    for (int mt = 0; mt < 4; ++mt)
      #pragma unroll
      for (int nt = 0; nt < 2; ++nt)
        sacc[mt][nt] = __builtin_amdgcn_mfma_f32_16x16x32_bf16(kf[mt], qf[nt], sacc[mt][nt], 0, 0, 0);

    #pragma unroll
    for (int mt = 0; mt < 4; ++mt)
      #pragma unroll
      for (int nt = 0; nt < 2; ++nt)
        #pragma unroll
        for (int r = 0; r < 4; ++r)
          sacc[mt][nt][r] += bv[mt][nt][r];

    __hip_bfloat16* pb = qbase;   // P[n][m], stride 72 (q+k region of this head)
    #pragma unroll
    for (int nt = 0; nt < 2; ++nt) {
      float mx = -1e30f;
      #pragma unroll
      for (int mt = 0; mt < 3; ++mt)
        #pragma unroll
        for (int r = 0; r < 4; ++r) mx = fmaxf(mx, sacc[mt][nt][r]);
      mx = fmaxf(mx, (quad == 0) ? sacc[3][nt][0] : -1e30f);   // m=48 only
      mx = fmaxf(mx, __shfl_xor(mx, 16));
      mx = fmaxf(mx, __shfl_xor(mx, 32));
      float sum = 0.f;
      #pragma unroll
      for (int mt = 0; mt < 3; ++mt)
        #pragma unroll
        for (int r = 0; r < 4; ++r) {
          float e = __expf(sacc[mt][nt][r] - mx);
          sacc[mt][nt][r] = e; sum += e;
        }
      {
        float e = (quad == 0) ? __expf(sacc[3][nt][0] - mx) : 0.f;
        sacc[3][nt][0] = e; sacc[3][nt][1] = 0.f; sacc[3][nt][2] = 0.f; sacc[3][nt][3] = 0.f;
        sum += e;
      }
      sum += __shfl_xor(sum, 16);
      sum += __shfl_xor(sum, 32);
      float inv = 1.f / sum;
      int n = (half*2 + nt)*16 + l15;
      #pragma unroll
      for (int mt = 0; mt < 4; ++mt) {
        short4v pk;
        #pragma unroll
        for (int r = 0; r < 4; ++r) pk[r] = f2bs(sacc[mt][nt][r] * inv);
        *(short4v*)(pb + n*72 + mt*16 + quad*4) = pk;
      }
    }

    // AV: A=V^T rows d, B=P rows n (own half) -> D[d][n]
    f32x4 oacc[2][2] = {};
    #pragma unroll
    for (int kt = 0; kt < 2; ++kt) {
      short8 vf[2], pf[2];
      #pragma unroll
      for (int dt = 0; dt < 2; ++dt)
        vf[dt] = *(const short8*)(&vT[h][dt*16 + l15][kt*32 + quad*8]);
      #pragma unroll
      for (int nc = 0; nc < 2; ++nc)
        pf[nc] = *(const short8*)(pb + ((half*2 + nc)*16 + l15)*72 + kt*32 + quad*8);
      #pragma unroll
      for (int dt = 0; dt < 2; ++dt)
        #pragma unroll
        for (int nc = 0; nc < 2; ++nc)
          oacc[dt][nc] = __builtin_amdgcn_mfma_f32_16x16x32_bf16(vf[dt], pf[nc], oacc[dt][nc], 0, 0, 0);
    }
    #pragma unroll
    for (int dt = 0; dt < 2; ++dt)
      #pragma unroll
      for (int nc = 0; nc < 2; ++nc) {
        int n = (half*2 + nc)*16 + l15;
        if (n < 49) {
          short4v pk;
          #pragma unroll
          for (int r = 0; r < 4; ++r) pk[r] = f2bs(oacc[dt][nc][r]);
          *(short4v*)(&hbuf[n][h*32 + dt*16 + quad*4]) = pk;
        }
      }

    // ---- prefetch for phase 4 (issued before the barrier; drain absorbs) ----
    const int ncol0 = wave * 16, n4 = ncol0 + l15;
    #pragma unroll
    for (int ks = 0; ks < 4; ++ks)
      pw[ks] = *(const short8*)(projwb + n4*128 + ks*32 + quad*8);
    #pragma unroll
    for (int mt = 0; mt < 4; ++mt) {
      #pragma unroll
      for (int r = 0; r < 4; ++r) {
        int m = mt*16 + quad*4 + r;
        float v = 0.f;
        if (m < 49) {
          int rr = m / 7, cc = m - rr * 7;
          int si = wi*7 + rr + 3; if (si >= 56) si -= 56;
          int sj = wj*7 + cc + 3; if (sj >= 56) sj -= 56;
          v = x[(b*3136 + si*56 + sj) * 128 + n4];
        }
        xres[mt][r] = v;
      }
    }
  }
  __syncthreads();

  // ---- phase 4: proj + shortcut -> x2 in REGISTERS (fp32) + fp32 LDS mirror ----
  f32x4 x2v[4];   // [mt]: m = mt*16+quad*4+r, f = wave*16+l15
  {
    const int n = wave * 16 + l15;
    f32x4 acc[4] = {};
    #pragma unroll
    for (int ks = 0; ks < 4; ++ks) {
      short8 af[4];
      #pragma unroll
      for (int mt = 0; mt < 4; ++mt)
        af[mt] = *(const short8*)(&hbuf[mt*16 + l15][ks*32 + quad*8]);
      #pragma unroll
      for (int mt = 0; mt < 4; ++mt)
        acc[mt] = __builtin_amdgcn_mfma_f32_16x16x32_bf16(af[mt], pw[ks], acc[mt], 0, 0, 0);
    }
    float pbv = projb[n];
    #pragma unroll
    for (int mt = 0; mt < 4; ++mt) {
      #pragma unroll
      for (int r = 0; r < 4; ++r) {
        int m = mt*16 + quad*4 + r;
        float v = 0.f;
        if (m < 49) v = acc[mt][r] + pbv + xres[mt][r];
        x2v[mt][r] = v;
        x2s[m*132 + n] = v;     // fp32 mirror for LN2 (overlays dead Q/K/P)
      }
    }
  }
  __syncthreads();

  // ---- phase 5: LN2 from x2s -> hbuf bf16 (hbuf o-tile dead now) ----
  {
    float g0 = n2g[lane], g1 = n2g[lane+64], e0 = n2b[lane], e1 = n2b[lane+64];
    for (int n = wave; n < 49; n += 8) {
      float v0 = x2s[n*132 + lane], v1 = x2s[n*132 + lane + 64];
      float s = v0 + v1, sq = v0*v0 + v1*v1;
      #pragma unroll
      for (int off = 32; off > 0; off >>= 1) {
        s  += __shfl_xor(s,  off);
        sq += __shfl_xor(sq, off);
      }
      float mean = s * 0.0078125f;
      float var  = sq * 0.0078125f - mean*mean;
      float rstd = rsqrtf(var + 1e-5f);
      hbuf[n][lane]    = __float2bfloat16((v0-mean)*rstd*g0 + e0);
      hbuf[n][lane+64] = __float2bfloat16((v1-mean)*rstd*g1 + e1);
    }
    __hip_bfloat16 z = __float2bfloat16(0.f);
    for (int n = 49 + wave; n < 64; n += 8) {   // zero pad rows for GEMM1
      hbuf[n][lane] = z; hbuf[n][lane+64] = z;
    }
  }

  // ---- prefetch w1 chunk-0 fragments (before the p5-end barrier) ----
  short8 w1f0[4][2];
  {
    const int jbl = wave * 32;
    #pragma unroll
    for (int ks = 0; ks < 4; ++ks)
      #pragma unroll
      for (int jt = 0; jt < 2; ++jt)
        w1f0[ks][jt] = *(const short8*)(w1b + (jbl + jt*16 + l15)*128 + ks*32 + quad*8);
  }
  __syncthreads();   // x2s reads done -> region A reusable as hidden buf

  // ---- phase 6: MLP, hidden in 2 chunks of 256; GEMM2 accumulates.
  //      Manually unrolled so w2/w1 fragment prefetches sit before barriers. ----
  f32x4 acc2[4] = {};   // [mt]: m = mt*16+quad*4+r, f = wave*16+l15
  short8 w2f[8];
  const int fb2 = wave * 16;

  // -- GEMM1 chunk 0 (prefetched weights) --
  {
    const int jbl = wave * 32;
    f32x4 acc1[2][4] = {};   // [jt][mt]
    #pragma unroll
    for (int ks = 0; ks < 4; ++ks) {
      short8 lf[4];
      #pragma unroll
      for (int mt = 0; mt < 4; ++mt)
        lf[mt] = *(const short8*)(&hbuf[mt*16 + l15][ks*32 + quad*8]);
      #pragma unroll
      for (int jt = 0; jt < 2; ++jt)
        #pragma unroll
        for (int mt = 0; mt < 4; ++mt)
          acc1[jt][mt] = __builtin_amdgcn_mfma_f32_16x16x32_bf16(w1f0[ks][jt], lf[mt], acc1[jt][mt], 0, 0, 0);
    }
    #pragma unroll
    for (int jt = 0; jt < 2; ++jt) {
      int j0l = jbl + jt*16 + quad*4;
      float bb[4];
      #pragma unroll
      for (int r = 0; r < 4; ++r) bb[r] = b1[j0l + r];
      #pragma unroll
      for (int mt = 0; mt < 4; ++mt) {
        int m = mt*16 + l15;
        short4v pk;
        #pragma unroll
        for (int r = 0; r < 4; ++r) pk[r] = f2bs(gelu_f(acc1[jt][mt][r] + bb[r]));
        *(short4v*)(hb + m*264 + j0l) = pk;
      }
    }
  }
  // prefetch w2 chunk-0 fragments (hidden by the hb-ready barrier drain)
  #pragma unroll
  for (int ks = 0; ks < 8; ++ks)
    w2f[ks] = *(const short8*)(w2b + (fb2 + l15)*512 + ks*32 + quad*8);
  __syncthreads();   // hb chunk 0 ready

  // -- GEMM2 partial, chunk 0 --
  #pragma unroll
  for (int ks = 0; ks < 8; ++ks) {
    short8 af[4];
    #pragma unroll
    for (int mt = 0; mt < 4; ++mt)
      af[mt] = *(const short8*)(hb + (mt*16 + l15)*264 + ks*32 + quad*8);
    #pragma unroll
    for (int mt = 0; mt < 4; ++mt)
      acc2[mt] = __builtin_amdgcn_mfma_f32_16x16x32_bf16(af[mt], w2f[ks], acc2[mt], 0, 0, 0);
  }
  __syncthreads();   // hb chunk 0 consumed, safe to overwrite

  // -- GEMM1 chunk 1 (weights loaded in-loop; VGPR pressure headroom) --
  {
    const int jbl = wave * 32;
    f32x4 acc1[2][4] = {};
    #pragma unroll
    for (int ks = 0; ks < 4; ++ks) {
      short8 lf[4];
      #pragma unroll
      for (int mt = 0; mt < 4; ++mt)
        lf[mt] = *(const short8*)(&hbuf[mt*16 + l15][ks*32 + quad*8]);
      #pragma unroll
      for (int jt = 0; jt < 2; ++jt) {
        short8 wf = *(const short8*)(w1b + (256 + jbl + jt*16 + l15)*128 + ks*32 + quad*8);
        #pragma unroll
        for (int mt = 0; mt < 4; ++mt)
          acc1[jt][mt] = __builtin_amdgcn_mfma_f32_16x16x32_bf16(wf, lf[mt], acc1[jt][mt], 0, 0, 0);
      }
    }
    #pragma unroll
    for (int jt = 0; jt < 2; ++jt) {
      int j0l = jbl + jt*16 + quad*4;
      float bb[4];
      #pragma unroll
      for (int r = 0; r < 4; ++r) bb[r] = b1[256 + j0l + r];
      #pragma unroll
      for (int mt = 0; mt < 4; ++mt) {
        int m = mt*16 + l15;
        short4v pk;
        #pragma unroll
        for (int r = 0; r < 4; ++r) pk[r] = f2bs(gelu_f(acc1[jt][mt][r] + bb[r]));
        *(short4v*)(hb + m*264 + j0l) = pk;
      }
    }
  }
  // prefetch w2 chunk-1 fragments (hidden by the hb-ready barrier drain)
  #pragma unroll
  for (int ks = 0; ks < 8; ++ks)
    w2f[ks] = *(const short8*)(w2b + (fb2 + l15)*512 + 256 + ks*32 + quad*8);
  __syncthreads();   // hb chunk 1 ready

  // -- GEMM2 partial, chunk 1 --
  #pragma unroll
  for (int ks = 0; ks < 8; ++ks) {
    short8 af[4];
    #pragma unroll
    for (int mt = 0; mt < 4; ++mt)
      af[mt] = *(const short8*)(hb + (mt*16 + l15)*264 + ks*32 + quad*8);
    #pragma unroll
    for (int mt = 0; mt < 4; ++mt)
      acc2[mt] = __builtin_amdgcn_mfma_f32_16x16x32_bf16(af[mt], w2f[ks], acc2[mt], 0, 0, 0);
  }

  // ---- epilogue: bias + register residual, scatter (roll +3) ----
  {
    const int f = fb2 + l15;
    const float bb = b2[f];
    #pragma unroll
    for (int mt = 0; mt < 4; ++mt) {
      #pragma unroll
      for (int r = 0; r < 4; ++r) {
        int m = mt*16 + quad*4 + r;
        if (m < 49) {
          int rr = m / 7, cc = m - rr * 7;
          int si = wi*7 + rr + 3; if (si >= 56) si -= 56;
          int sj = wj*7 + cc + 3; if (sj >= 56) sj -= 56;
          int o = (b*3136 + si*56 + sj) * 128 + f;
          out[o] = acc2[mt][r] + bb + x2v[mt][r];
        }
      }
    }
  }
}

extern "C" void kernel_launch(void* const* d_in, const int* in_sizes, int n_in,
                              void* d_out, int out_size, void* d_ws, size_t ws_size,
                              hipStream_t stream) {
  const float* x     = (const float*)d_in[0];
  const float* n1g   = (const float*)d_in[3];
  const float* n1b   = (const float*)d_in[4];
  const float* qkvw  = (const float*)d_in[5];
  const float* qkvb  = (const float*)d_in[6];
  const float* tab   = (const float*)d_in[7];
  const int*   ridx  = (const int*)d_in[8];
  const float* projw = (const float*)d_in[9];
  const float* projb = (const float*)d_in[10];
  const float* n2g   = (const float*)d_in[11];
  const float* n2b   = (const float*)d_in[12];
  const float* w1    = (const float*)d_in[13];
  const float* b1    = (const float*)d_in[14];
  const float* w2    = (const float*)d_in[15];
  const float* b2    = (const float*)d_in[16];
  float* outp = (float*)d_out;

  __hip_bfloat16* wsb = (__hip_bfloat16*)d_ws;
  float* biasT = (float*)((char*)d_ws + BIAS_BYTE_OFF);

  hipLaunchKernelGGL(conv_kernel, dim3(832), dim3(256), 0, stream,
                     qkvw, projw, w1, w2, tab, ridx, wsb, biasT);
  hipLaunchKernelGGL(fused_kernel, dim3(NWIN), dim3(512), 0, stream,
                     x, n1g, n1b, wsb + QKVW_OFF, qkvb, biasT, wsb + PROJW_OFF, projb,
                     n2g, n2b, wsb + W1_OFF, b1, wsb + W2_OFF, b2, outp);
}